// Round 8
// baseline (163.936 us; speedup 1.0000x reference)
//
#include <hip/hip_runtime.h>
#include <math.h>

#define NV 720
#define NU 736
#define NXY 512

// ---------------- Stage 1+2: cosine weight + Ram-Lak Toeplitz GEMM (+ trig table) ------
__global__ __launch_bounds__(192) void filter_kernel(const float* __restrict__ sino,
                                                     float* __restrict__ Q,
                                                     float4* __restrict__ trig) {
    __shared__ float s4[2][368][4];   // [parity][m][view]
    __shared__ float wco[736];        // wco[i] = -1/(pi*(2i-735)*DU)^2
    const int v0 = blockIdx.x * 4;
    const int t = threadIdx.x;

    if (t < 4) {
        int v = v0 + t;
        float beta = (float)((double)v * (2.0 * M_PI / 720.0));
        float cb = cosf(beta), sb = sinf(beta);
        const float K = (float)(1085.6 / 1.2858);   // DSD/DU
        trig[v] = make_float4(cb * K, sb * K, cb, sb);
    }
    for (int i = t; i < 736; i += 192) {
        double n = (double)(2 * i - 735);
        double a = M_PI * n * 1.2858;
        wco[i] = (float)(-1.0 / (a * a));
    }
    const float DSD2 = (float)(1085.6 * 1085.6);
    for (int vv = 0; vv < 4; ++vv) {
        for (int u = t; u < 736; u += 192) {
            float us = ((float)u - 367.5f) * 1.2858f;
            float cw = 1085.6f / sqrtf(DSD2 + us * us);
            s4[u & 1][u >> 1][vv] = sino[(v0 + vv) * NU + u] * cw;
        }
    }
    __syncthreads();

    if (t < 184) {
        const int pj = (t < 92) ? 1 : 0;
        const int J0 = (t < 92) ? t : t - 92;
        const int q = 1 - pj;
        float acc[4][4];
        #pragma unroll
        for (int r = 0; r < 4; ++r)
            #pragma unroll
            for (int vv = 0; vv < 4; ++vv) acc[r][vv] = 0.0f;

        const int ibase0 = J0 + 367 + pj;
        #pragma unroll 4
        for (int m = 0; m < 368; ++m) {
            const float4 sv = *(const float4*)&s4[q][m][0];
            const int ib = ibase0 - m;
            const float w0 = wco[ib];
            const float w1 = wco[ib + 92];
            const float w2 = wco[ib + 184];
            const float w3 = wco[ib + 276];
            acc[0][0] = fmaf(w0, sv.x, acc[0][0]);
            acc[0][1] = fmaf(w0, sv.y, acc[0][1]);
            acc[0][2] = fmaf(w0, sv.z, acc[0][2]);
            acc[0][3] = fmaf(w0, sv.w, acc[0][3]);
            acc[1][0] = fmaf(w1, sv.x, acc[1][0]);
            acc[1][1] = fmaf(w1, sv.y, acc[1][1]);
            acc[1][2] = fmaf(w1, sv.z, acc[1][2]);
            acc[1][3] = fmaf(w1, sv.w, acc[1][3]);
            acc[2][0] = fmaf(w2, sv.x, acc[2][0]);
            acc[2][1] = fmaf(w2, sv.y, acc[2][1]);
            acc[2][2] = fmaf(w2, sv.z, acc[2][2]);
            acc[2][3] = fmaf(w2, sv.w, acc[2][3]);
            acc[3][0] = fmaf(w3, sv.x, acc[3][0]);
            acc[3][1] = fmaf(w3, sv.y, acc[3][1]);
            acc[3][2] = fmaf(w3, sv.z, acc[3][2]);
            acc[3][3] = fmaf(w3, sv.w, acc[3][3]);
        }
        const float H0 = (float)(1.0 / (4.0 * 1.2858 * 1.2858));
        #pragma unroll
        for (int r = 0; r < 4; ++r) {
            const float4 c = *(const float4*)&s4[pj][J0 + 92 * r][0];
            acc[r][0] = fmaf(H0, c.x, acc[r][0]);
            acc[r][1] = fmaf(H0, c.y, acc[r][1]);
            acc[r][2] = fmaf(H0, c.z, acc[r][2]);
            acc[r][3] = fmaf(H0, c.w, acc[r][3]);
        }
        #pragma unroll
        for (int r = 0; r < 4; ++r) {
            const int j = 2 * (J0 + 92 * r) + pj;
            #pragma unroll
            for (int vv = 0; vv < 4; ++vv)
                Q[(v0 + vv) * NU + j] = acc[r][vv] * 1.2858f;
        }
    }
}

// ---------------- Stage 3: backprojection (8x8 wave tiles to kill line replay) ---------
// EVIDENCE (R6/R7): bp is bound ~100us by per-cache-line replay of divergent gathers:
// VALU diet (R6) and gather-instr halving (R7) both left time flat. A 1x64-row wave
// spans ~70 detector bins = 5-6 L1 lines/load. An 8x8-pixel wave tile spans
// ~8(|cb|+|sb|) = 8-11.3 bins = 1-2 lines/load -> ~4x fewer replays.
// Lane map: wave w of block covers tile (8x8); pixel arithmetic/view order BIT-IDENTICAL
// to the passing R7 kernel (pure lane permutation; per-pixel sums private) -> absmax
// must stay 3.051758e-04. One pixel per lane (R5 lesson); no reassociation (R4 lesson).
__global__ __launch_bounds__(256) void bp_kernel(const float* __restrict__ Q,
                                                 const float4* __restrict__ trig,
                                                 float* __restrict__ out) {
    const int b = blockIdx.x;
    const int h = b & 1;                      // view half: [0,360) or [360,720)
    const int blk = b >> 1;                   // 1024 pixel-blocks of 16x16
    const int bx = blk >> 5;                  // 32x32 grid of blocks
    const int by = blk & 31;
    const int t = threadIdx.x;
    const int w = t >> 6;                     // wave 0..3 -> 2x2 arrangement of 8x8 tiles
    const int l = t & 63;
    const int ix = (bx << 4) + ((w >> 1) << 3) + (l >> 3);
    const int jy = (by << 4) + ((w & 1) << 3) + (l & 7);

    const float dx = 400.0f / 512.0f;         // 0.78125 exact
    const float X  = ((float)ix - 255.5f) * dx;
    const float Y  = ((float)jy - 255.5f) * dx;
    const float nY = -Y;

    float acc = 0.0f;
    const float* qrow = Q + h * 360 * NU;
    const float4* tvp = trig + h * 360;
    const bool inr = fmaf(X, X, Y * Y) <= 236.5f * 236.5f;

    if (__all(inr)) {
        #pragma unroll 4
        for (int v = 0; v < 360; ++v) {
            const float4 tv = tvp[v];
            float t2 = fmaf(tv.x, X, tv.y * Y);                 // R3-exact
            float D  = fmaf(tv.w, X, fmaf(tv.z, nY, 595.0f));   // R3-exact
            float rD = __builtin_amdgcn_rcpf(D);
            float fidx = fmaf(t2, rD, 367.5f);
            unsigned i0 = (unsigned)(int)fidx;                  // in [0,734] by geometry
            float f = __builtin_amdgcn_fractf(fidx);
            float2 qq = *(const float2*)(qrow + i0);            // global_load_dwordx2
            float val = fmaf(f, qq.y - qq.x, qq.x);
            acc = fmaf(rD * rD, val, acc);
            qrow += NU;
        }
    } else {
        #pragma unroll 4
        for (int v = 0; v < 360; ++v) {
            const float4 tv = tvp[v];
            float t2 = fmaf(tv.x, X, tv.y * Y);
            float D  = fmaf(tv.w, X, fmaf(tv.z, nY, 595.0f));
            float rD = __builtin_amdgcn_rcpf(D);
            float fidx = fmaf(t2, rD, 367.5f);
            int i0 = (int)fidx;
            int i0c = min(max(i0, 0), NU - 2);                  // v_med3_i32
            float f = __builtin_amdgcn_fractf(fidx);
            float2 qq = *(const float2*)(qrow + i0c);           // global_load_dwordx2
            float val = fmaf(f, qq.y - qq.x, qq.x);
            float g = rD * rD;
            float cen = fidx - 367.5f;
            g = (__builtin_fabsf(cen) <= 367.5f) ? g : 0.0f;
            acc = fmaf(g, val, acc);
            qrow += NU;
        }
    }
    const float SC = (float)(595.0 * 595.0 * 0.5 * (2.0 * M_PI / 720.0));
    unsafeAtomicAdd(&out[ix * NXY + jy], acc * SC);
}

extern "C" void kernel_launch(void* const* d_in, const int* in_sizes, int n_in,
                              void* d_out, int out_size, void* d_ws, size_t ws_size,
                              hipStream_t stream) {
    const float* sino = (const float*)d_in[0];
    float* out = (float*)d_out;
    float* Q = (float*)d_ws;                                          // 720*736*4 = 2.12 MB
    float4* trig = (float4*)((char*)d_ws + NV * NU * sizeof(float));  // +11.5 KB (16B aligned)

    filter_kernel<<<NV / 4, 192, 0, stream>>>(sino, Q, trig);
    hipMemsetAsync(out, 0, (size_t)NXY * NXY * sizeof(float), stream);  // atomic targets
    bp_kernel<<<2 * (NXY * NXY) / 256, 256, 0, stream>>>(Q, trig, out);
}

// Round 9
// 156.124 us; speedup vs baseline: 1.0500x; 1.0500x over previous
//
#include <hip/hip_runtime.h>
#include <math.h>

#define NV 720
#define NU 736
#define NXY 512

// ---------------- Stage 1+2: cosine weight + Ram-Lak Toeplitz GEMM (+ trig table) ------
__global__ __launch_bounds__(192) void filter_kernel(const float* __restrict__ sino,
                                                     float* __restrict__ Q,
                                                     float4* __restrict__ trig) {
    __shared__ float s4[2][368][4];   // [parity][m][view]
    __shared__ float wco[736];        // wco[i] = -1/(pi*(2i-735)*DU)^2
    const int v0 = blockIdx.x * 4;
    const int t = threadIdx.x;

    if (t < 4) {
        int v = v0 + t;
        float beta = (float)((double)v * (2.0 * M_PI / 720.0));
        float cb = cosf(beta), sb = sinf(beta);
        const float K = (float)(1085.6 / 1.2858);   // DSD/DU
        trig[v] = make_float4(cb * K, sb * K, cb, sb);
    }
    for (int i = t; i < 736; i += 192) {
        double n = (double)(2 * i - 735);
        double a = M_PI * n * 1.2858;
        wco[i] = (float)(-1.0 / (a * a));
    }
    const float DSD2 = (float)(1085.6 * 1085.6);
    for (int vv = 0; vv < 4; ++vv) {
        for (int u = t; u < 736; u += 192) {
            float us = ((float)u - 367.5f) * 1.2858f;
            float cw = 1085.6f / sqrtf(DSD2 + us * us);
            s4[u & 1][u >> 1][vv] = sino[(v0 + vv) * NU + u] * cw;
        }
    }
    __syncthreads();

    if (t < 184) {
        const int pj = (t < 92) ? 1 : 0;
        const int J0 = (t < 92) ? t : t - 92;
        const int q = 1 - pj;
        float acc[4][4];
        #pragma unroll
        for (int r = 0; r < 4; ++r)
            #pragma unroll
            for (int vv = 0; vv < 4; ++vv) acc[r][vv] = 0.0f;

        const int ibase0 = J0 + 367 + pj;
        #pragma unroll 4
        for (int m = 0; m < 368; ++m) {
            const float4 sv = *(const float4*)&s4[q][m][0];
            const int ib = ibase0 - m;
            const float w0 = wco[ib];
            const float w1 = wco[ib + 92];
            const float w2 = wco[ib + 184];
            const float w3 = wco[ib + 276];
            acc[0][0] = fmaf(w0, sv.x, acc[0][0]);
            acc[0][1] = fmaf(w0, sv.y, acc[0][1]);
            acc[0][2] = fmaf(w0, sv.z, acc[0][2]);
            acc[0][3] = fmaf(w0, sv.w, acc[0][3]);
            acc[1][0] = fmaf(w1, sv.x, acc[1][0]);
            acc[1][1] = fmaf(w1, sv.y, acc[1][1]);
            acc[1][2] = fmaf(w1, sv.z, acc[1][2]);
            acc[1][3] = fmaf(w1, sv.w, acc[1][3]);
            acc[2][0] = fmaf(w2, sv.x, acc[2][0]);
            acc[2][1] = fmaf(w2, sv.y, acc[2][1]);
            acc[2][2] = fmaf(w2, sv.z, acc[2][2]);
            acc[2][3] = fmaf(w2, sv.w, acc[2][3]);
            acc[3][0] = fmaf(w3, sv.x, acc[3][0]);
            acc[3][1] = fmaf(w3, sv.y, acc[3][1]);
            acc[3][2] = fmaf(w3, sv.z, acc[3][2]);
            acc[3][3] = fmaf(w3, sv.w, acc[3][3]);
        }
        const float H0 = (float)(1.0 / (4.0 * 1.2858 * 1.2858));
        #pragma unroll
        for (int r = 0; r < 4; ++r) {
            const float4 c = *(const float4*)&s4[pj][J0 + 92 * r][0];
            acc[r][0] = fmaf(H0, c.x, acc[r][0]);
            acc[r][1] = fmaf(H0, c.y, acc[r][1]);
            acc[r][2] = fmaf(H0, c.z, acc[r][2]);
            acc[r][3] = fmaf(H0, c.w, acc[r][3]);
        }
        #pragma unroll
        for (int r = 0; r < 4; ++r) {
            const int j = 2 * (J0 + 92 * r) + pj;
            #pragma unroll
            for (int vv = 0; vv < 4; ++vv)
                Q[(v0 + vv) * NU + j] = acc[r][vv] * 1.2858f;
        }
    }
}

// ---------------- Stage 3: backprojection — NO divergent loads in the hot loop ---------
// EVIDENCE (R3/R6/R7/R8): bp pinned at ~103us across VALU diet, gather fusion, and
// footprint tiling; VALUBusy fell 92->71% at constant time. Hypothesis: the per-lane
// address-divergence resolution of vector loads is the invariant cost. This version
// removes it for interior waves: one COALESCED global_load_dword stages a 64-bin
// window (lane l holds Q[row+base+l]), then two ds_bpermute_b32 route Q[i0],Q[i0+1]
// to each lane. Fetched values are bit-identical.
// WINDOW PROOF (8x8 interior tile, all r<=236.5mm, disk is convex): along any
// intra-tile segment |grad fidx| <= (K/D)(1+|t|/D) <= (844.3/358.5)(1+0.433)
// = 3.38 bins/mm; tile diagonal 7*sqrt(2)*0.78125 = 7.73mm -> spread <= 26.1 bins;
// + floor slack 1 + lerp 1 => need +-28. base = readfirstlane(i0)-32 gives margins
// 32/31. Clamp base to [0,672]: if clamped low (i0_l0<32) all i0<=i0_l0+28<=59<=63 ok;
// if clamped high (i0_l0>704) all i0>=676>=672 and i0+1<=735=672+63 ok.
// Exterior waves (~6%, image corners) keep the R7 divergent-gather path verbatim.
// NUMERICS: R3-exact chains; no reassociation (R4 lesson); 1 px/lane (R5 lesson).
__global__ __launch_bounds__(256) void bp_kernel(const float* __restrict__ Q,
                                                 const float4* __restrict__ trig,
                                                 float* __restrict__ out) {
    const int b = blockIdx.x;
    const int h = b & 1;                      // view half: [0,360) or [360,720)
    const int blk = b >> 1;                   // 1024 pixel-blocks of 16x16
    const int bx = blk >> 5;                  // 32x32 grid of blocks
    const int by = blk & 31;
    const int t = threadIdx.x;
    const int w = t >> 6;                     // wave 0..3 -> 2x2 arrangement of 8x8 tiles
    const int l = t & 63;
    const int ix = (bx << 4) + ((w >> 1) << 3) + (l >> 3);
    const int jy = (by << 4) + ((w & 1) << 3) + (l & 7);

    const float dx = 400.0f / 512.0f;         // 0.78125 exact
    const float X  = ((float)ix - 255.5f) * dx;
    const float Y  = ((float)jy - 255.5f) * dx;
    const float nY = -Y;

    float acc = 0.0f;
    const float* qrow = Q + h * 360 * NU;
    const float4* tvp = trig + h * 360;
    const bool inr = fmaf(X, X, Y * Y) <= 236.5f * 236.5f;

    if (__all(inr)) {
        #pragma unroll 4
        for (int v = 0; v < 360; ++v) {
            const float4 tv = tvp[v];
            float t2 = fmaf(tv.x, X, tv.y * Y);                 // R3-exact
            float D  = fmaf(tv.w, X, fmaf(tv.z, nY, 595.0f));   // R3-exact
            float rD = __builtin_amdgcn_rcpf(D);
            float fidx = fmaf(t2, rD, 367.5f);
            int i0 = (int)fidx;                                 // in [1,733] by geometry
            int base = __builtin_amdgcn_readfirstlane(i0) - 32; // scalar
            base = min(max(base, 0), NU - 64);                  // scalar clamp
            float qw = qrow[base + l];                          // COALESCED dword load
            float f = __builtin_amdgcn_fractf(fidx);
            int rel = (i0 - base) << 2;                         // byte addr for bpermute
            float q0 = __hip_ds_bpermutef(rel, qw);             // lane rel>>2 -> Q[i0]
            float q1 = __hip_ds_bpermutef(rel + 4, qw);         //              Q[i0+1]
            float val = fmaf(f, q1 - q0, q0);
            acc = fmaf(rD * rD, val, acc);
            qrow += NU;
        }
    } else {
        #pragma unroll 4
        for (int v = 0; v < 360; ++v) {
            const float4 tv = tvp[v];
            float t2 = fmaf(tv.x, X, tv.y * Y);
            float D  = fmaf(tv.w, X, fmaf(tv.z, nY, 595.0f));
            float rD = __builtin_amdgcn_rcpf(D);
            float fidx = fmaf(t2, rD, 367.5f);
            int i0 = (int)fidx;
            int i0c = min(max(i0, 0), NU - 2);                  // v_med3_i32
            float f = __builtin_amdgcn_fractf(fidx);
            float2 qq = *(const float2*)(qrow + i0c);           // divergent dwordx2 (R7)
            float val = fmaf(f, qq.y - qq.x, qq.x);
            float g = rD * rD;
            float cen = fidx - 367.5f;
            g = (__builtin_fabsf(cen) <= 367.5f) ? g : 0.0f;
            acc = fmaf(g, val, acc);
            qrow += NU;
        }
    }
    const float SC = (float)(595.0 * 595.0 * 0.5 * (2.0 * M_PI / 720.0));
    unsafeAtomicAdd(&out[ix * NXY + jy], acc * SC);
}

extern "C" void kernel_launch(void* const* d_in, const int* in_sizes, int n_in,
                              void* d_out, int out_size, void* d_ws, size_t ws_size,
                              hipStream_t stream) {
    const float* sino = (const float*)d_in[0];
    float* out = (float*)d_out;
    float* Q = (float*)d_ws;                                          // 720*736*4 = 2.12 MB
    float4* trig = (float4*)((char*)d_ws + NV * NU * sizeof(float));  // +11.5 KB (16B aligned)

    filter_kernel<<<NV / 4, 192, 0, stream>>>(sino, Q, trig);
    hipMemsetAsync(out, 0, (size_t)NXY * NXY * sizeof(float), stream);  // atomic targets
    bp_kernel<<<2 * (NXY * NXY) / 256, 256, 0, stream>>>(Q, trig, out);
}

// Round 10
// 140.400 us; speedup vs baseline: 1.1676x; 1.1120x over previous
//
#include <hip/hip_runtime.h>
#include <math.h>

#define NV 720
#define NU 736
#define NXY 512

// ---------------- Stage 1+2: cosine weight + Ram-Lak Toeplitz GEMM (+ trig table) ------
__global__ __launch_bounds__(192) void filter_kernel(const float* __restrict__ sino,
                                                     float* __restrict__ Q,
                                                     float4* __restrict__ trig) {
    __shared__ float s4[2][368][4];   // [parity][m][view]
    __shared__ float wco[736];        // wco[i] = -1/(pi*(2i-735)*DU)^2
    const int v0 = blockIdx.x * 4;
    const int t = threadIdx.x;

    if (t < 4) {
        int v = v0 + t;
        float beta = (float)((double)v * (2.0 * M_PI / 720.0));
        float cb = cosf(beta), sb = sinf(beta);
        const float K = (float)(1085.6 / 1.2858);   // DSD/DU
        trig[v] = make_float4(cb * K, sb * K, cb, sb);
    }
    for (int i = t; i < 736; i += 192) {
        double n = (double)(2 * i - 735);
        double a = M_PI * n * 1.2858;
        wco[i] = (float)(-1.0 / (a * a));
    }
    const float DSD2 = (float)(1085.6 * 1085.6);
    for (int vv = 0; vv < 4; ++vv) {
        for (int u = t; u < 736; u += 192) {
            float us = ((float)u - 367.5f) * 1.2858f;
            float cw = 1085.6f / sqrtf(DSD2 + us * us);
            s4[u & 1][u >> 1][vv] = sino[(v0 + vv) * NU + u] * cw;
        }
    }
    __syncthreads();

    if (t < 184) {
        const int pj = (t < 92) ? 1 : 0;
        const int J0 = (t < 92) ? t : t - 92;
        const int q = 1 - pj;
        float acc[4][4];
        #pragma unroll
        for (int r = 0; r < 4; ++r)
            #pragma unroll
            for (int vv = 0; vv < 4; ++vv) acc[r][vv] = 0.0f;

        const int ibase0 = J0 + 367 + pj;
        #pragma unroll 4
        for (int m = 0; m < 368; ++m) {
            const float4 sv = *(const float4*)&s4[q][m][0];
            const int ib = ibase0 - m;
            const float w0 = wco[ib];
            const float w1 = wco[ib + 92];
            const float w2 = wco[ib + 184];
            const float w3 = wco[ib + 276];
            acc[0][0] = fmaf(w0, sv.x, acc[0][0]);
            acc[0][1] = fmaf(w0, sv.y, acc[0][1]);
            acc[0][2] = fmaf(w0, sv.z, acc[0][2]);
            acc[0][3] = fmaf(w0, sv.w, acc[0][3]);
            acc[1][0] = fmaf(w1, sv.x, acc[1][0]);
            acc[1][1] = fmaf(w1, sv.y, acc[1][1]);
            acc[1][2] = fmaf(w1, sv.z, acc[1][2]);
            acc[1][3] = fmaf(w1, sv.w, acc[1][3]);
            acc[2][0] = fmaf(w2, sv.x, acc[2][0]);
            acc[2][1] = fmaf(w2, sv.y, acc[2][1]);
            acc[2][2] = fmaf(w2, sv.z, acc[2][2]);
            acc[2][3] = fmaf(w2, sv.w, acc[2][3]);
            acc[3][0] = fmaf(w3, sv.x, acc[3][0]);
            acc[3][1] = fmaf(w3, sv.y, acc[3][1]);
            acc[3][2] = fmaf(w3, sv.z, acc[3][2]);
            acc[3][3] = fmaf(w3, sv.w, acc[3][3]);
        }
        const float H0 = (float)(1.0 / (4.0 * 1.2858 * 1.2858));
        #pragma unroll
        for (int r = 0; r < 4; ++r) {
            const float4 c = *(const float4*)&s4[pj][J0 + 92 * r][0];
            acc[r][0] = fmaf(H0, c.x, acc[r][0]);
            acc[r][1] = fmaf(H0, c.y, acc[r][1]);
            acc[r][2] = fmaf(H0, c.z, acc[r][2]);
            acc[r][3] = fmaf(H0, c.w, acc[r][3]);
        }
        #pragma unroll
        for (int r = 0; r < 4; ++r) {
            const int j = 2 * (J0 + 92 * r) + pj;
            #pragma unroll
            for (int vv = 0; vv < 4; ++vv)
                Q[(v0 + vv) * NU + j] = acc[r][vv] * 1.2858f;
        }
    }
}

// ---------------- Stage 3: backprojection — 4-fold rotation symmetry -------------------
// Identity: t(P,b+90) = s(P,b), s(P,b+90) = -t(P,b); R(P) = (Y,-X) is exact on the grid
// (center 255.5 off-grid). Thread owns P_m = R^m(P0), m=0..3 (same radius). Per base
// view v in [0,180): a = t0 = fmaf(cb,X,sb*Y), b = s0 = fmaf(cb,Y,-sb*X) give
//   (t,D): m0 (a, 595-b)  m1 (b, 595+a)  m2 (-a, 595+b)  m3 (-b, 595-a)
// acc(P_j) += g_m * lerp(Q[v+180k], idx_m) with m = (j+k)&3 -> 16 contributions/iter on
// 4 geometries. Gathers stay R9-style: coalesced 64-bin window (same voffset for all 4
// rows of a given m) + 2 bpermutes. Window proof as R9 (8x8 tile, r<=236.5 -> spread<=28).
// EXTERIOR waves (~13%, corners): NO symmetry — R7-exact per-view chains, gates, and
// divergent dwordx2 (R4 lesson: gate arithmetic must stay bit-exact). 4-way view split
// via atomics = R5's pattern. Interior reorder only wiggles lerp weights (no gates).
__global__ __launch_bounds__(256) void bp_kernel(const float* __restrict__ Q,
                                                 const float4* __restrict__ trig,
                                                 float* __restrict__ out) {
    const int b = blockIdx.x;
    const int c = b & 3;                      // view chunk
    const int blk = b >> 2;                   // 256 quadrant blocks of 16x16
    const int bx = blk >> 4;
    const int by = blk & 15;
    const int t = threadIdx.x;
    const int w = t >> 6;
    const int l = t & 63;
    const int iq = (bx << 4) + ((w >> 1) << 3) + (l >> 3);   // [0,256)
    const int jq = (by << 4) + ((w & 1) << 3) + (l & 7);     // [0,256)

    const float dx = 400.0f / 512.0f;         // 0.78125 exact
    const float X = ((float)iq - 255.5f) * dx;   // < 0
    const float Y = ((float)jq - 255.5f) * dx;   // < 0
    const float Kc = (float)(1085.6 / 1.2858);

    float acc0 = 0.0f, acc1 = 0.0f, acc2 = 0.0f, acc3 = 0.0f;
    const bool inr = fmaf(X, X, Y * Y) <= 236.5f * 236.5f;

    if (__all(inr)) {
        // ---- interior: symmetric path, views {v, v+180, v+360, v+540}, v in chunk ----
        const int v_lo = 45 * c;
        const float* qv0 = Q + (v_lo)       * NU;
        const float* qv1 = Q + (v_lo + 180) * NU;
        const float* qv2 = Q + (v_lo + 360) * NU;
        const float* qv3 = Q + (v_lo + 540) * NU;
        const float4* tvp = trig + v_lo;
        for (int it = 0; it < 45; ++it) {
            const float4 tv = tvp[it];                    // cb = tv.z, sb = tv.w
            float a = fmaf(tv.z, X, tv.w * Y);            // t0
            float bb = fmaf(tv.z, Y, -tv.w * X);          // s0
            float aK = a * Kc, bK = bb * Kc;
            float D0 = 595.0f - bb, D1 = 595.0f + a, D2 = 595.0f + bb, D3 = 595.0f - a;
            float r0 = __builtin_amdgcn_rcpf(D0);
            float r1 = __builtin_amdgcn_rcpf(D1);
            float r2 = __builtin_amdgcn_rcpf(D2);
            float r3 = __builtin_amdgcn_rcpf(D3);
            float fi0 = fmaf(aK,  r0, 367.5f);
            float fi1 = fmaf(bK,  r1, 367.5f);
            float fi2 = fmaf(-aK, r2, 367.5f);
            float fi3 = fmaf(-bK, r3, 367.5f);
            int i0 = (int)fi0, i1 = (int)fi1, i2 = (int)fi2, i3 = (int)fi3;
            float f0 = __builtin_amdgcn_fractf(fi0);
            float f1 = __builtin_amdgcn_fractf(fi1);
            float f2 = __builtin_amdgcn_fractf(fi2);
            float f3 = __builtin_amdgcn_fractf(fi3);
            int b0 = min(max(__builtin_amdgcn_readfirstlane(i0) - 32, 0), NU - 64);
            int b1 = min(max(__builtin_amdgcn_readfirstlane(i1) - 32, 0), NU - 64);
            int b2 = min(max(__builtin_amdgcn_readfirstlane(i2) - 32, 0), NU - 64);
            int b3 = min(max(__builtin_amdgcn_readfirstlane(i3) - 32, 0), NU - 64);
            int base[4] = {b0, b1, b2, b3};
            int rel4[4] = {(i0 - b0) << 2, (i1 - b1) << 2, (i2 - b2) << 2, (i3 - b3) << 2};
            float ff[4] = {f0, f1, f2, f3};
            float gg[4] = {r0 * r0, r1 * r1, r2 * r2, r3 * r3};
            float qw[4][4];
            #pragma unroll
            for (int m = 0; m < 4; ++m) {
                int off = base[m] + l;                    // uniform base + lane
                qw[m][0] = qv0[off];                      // coalesced dword loads
                qw[m][1] = qv1[off];
                qw[m][2] = qv2[off];
                qw[m][3] = qv3[off];
            }
            float* accp[4] = {&acc0, &acc1, &acc2, &acc3};
            #pragma unroll
            for (int m = 0; m < 4; ++m) {
                #pragma unroll
                for (int k = 0; k < 4; ++k) {
                    float q0 = __hip_ds_bpermutef(rel4[m], qw[m][k]);
                    float q1 = __hip_ds_bpermutef(rel4[m] + 4, qw[m][k]);
                    float val = fmaf(ff[m], q1 - q0, q0);
                    *accp[(m - k) & 3] = fmaf(gg[m], val, *accp[(m - k) & 3]);
                }
            }
            qv0 += NU; qv1 += NU; qv2 += NU; qv3 += NU;
        }
    } else {
        // ---- exterior: R7-exact per-view chains for the 4 pixels, views [180c,180c+180)
        const float pX[4] = {X, Y, -X, -Y};
        const float pY[4] = {Y, -X, -Y, X};
        float* accp[4] = {&acc0, &acc1, &acc2, &acc3};
        const int u_lo = 180 * c;
        const float* qr = Q + u_lo * NU;
        const float4* tvp = trig + u_lo;
        for (int u = 0; u < 180; ++u) {
            const float4 tv = tvp[u];
            #pragma unroll
            for (int m = 0; m < 4; ++m) {
                float Xm = pX[m], Ym = pY[m];
                float t2 = fmaf(tv.x, Xm, tv.y * Ym);               // R3-exact
                float D  = fmaf(tv.w, Xm, fmaf(tv.z, -Ym, 595.0f)); // R3-exact
                float rD = __builtin_amdgcn_rcpf(D);
                float fidx = fmaf(t2, rD, 367.5f);
                int i0 = (int)fidx;
                int i0c = min(max(i0, 0), NU - 2);                  // v_med3_i32
                float f = __builtin_amdgcn_fractf(fidx);
                float2 qq = *(const float2*)(qr + i0c);             // divergent dwordx2
                float val = fmaf(f, qq.y - qq.x, qq.x);
                float g = rD * rD;
                float cen = fidx - 367.5f;
                g = (__builtin_fabsf(cen) <= 367.5f) ? g : 0.0f;
                *accp[m] = fmaf(g, val, *accp[m]);
            }
            qr += NU;
        }
    }
    const float SC = (float)(595.0 * 595.0 * 0.5 * (2.0 * M_PI / 720.0));
    const int ir = 511 - iq, jr = 511 - jq;
    unsafeAtomicAdd(&out[iq * NXY + jq], acc0 * SC);   // P0 = (iq, jq)
    unsafeAtomicAdd(&out[jq * NXY + ir], acc1 * SC);   // P1 = (jq, 511-iq)
    unsafeAtomicAdd(&out[ir * NXY + jr], acc2 * SC);   // P2 = (511-iq, 511-jq)
    unsafeAtomicAdd(&out[jr * NXY + iq], acc3 * SC);   // P3 = (511-jq, iq)
}

extern "C" void kernel_launch(void* const* d_in, const int* in_sizes, int n_in,
                              void* d_out, int out_size, void* d_ws, size_t ws_size,
                              hipStream_t stream) {
    const float* sino = (const float*)d_in[0];
    float* out = (float*)d_out;
    float* Q = (float*)d_ws;                                          // 720*736*4 = 2.12 MB
    float4* trig = (float4*)((char*)d_ws + NV * NU * sizeof(float));  // +11.5 KB (16B aligned)

    filter_kernel<<<NV / 4, 192, 0, stream>>>(sino, Q, trig);
    hipMemsetAsync(out, 0, (size_t)NXY * NXY * sizeof(float), stream);  // atomic targets
    bp_kernel<<<1024, 256, 0, stream>>>(Q, trig, out);
}

// Round 11
// 138.053 us; speedup vs baseline: 1.1875x; 1.0170x over previous
//
#include <hip/hip_runtime.h>
#include <math.h>

#define NV 720
#define NU 736
#define NXY 512

// ---------------- Stage 1+2: cosine weight + Ram-Lak Toeplitz GEMM (+ trig table) ------
__global__ __launch_bounds__(192) void filter_kernel(const float* __restrict__ sino,
                                                     float* __restrict__ Q,
                                                     float4* __restrict__ trig) {
    __shared__ float s4[2][368][4];   // [parity][m][view]
    __shared__ float wco[736];        // wco[i] = -1/(pi*(2i-735)*DU)^2
    const int v0 = blockIdx.x * 4;
    const int t = threadIdx.x;

    if (t < 4) {
        int v = v0 + t;
        float beta = (float)((double)v * (2.0 * M_PI / 720.0));
        float cb = cosf(beta), sb = sinf(beta);
        const float K = (float)(1085.6 / 1.2858);   // DSD/DU
        trig[v] = make_float4(cb * K, sb * K, cb, sb);
    }
    for (int i = t; i < 736; i += 192) {
        double n = (double)(2 * i - 735);
        double a = M_PI * n * 1.2858;
        wco[i] = (float)(-1.0 / (a * a));
    }
    const float DSD2 = (float)(1085.6 * 1085.6);
    for (int vv = 0; vv < 4; ++vv) {
        for (int u = t; u < 736; u += 192) {
            float us = ((float)u - 367.5f) * 1.2858f;
            float cw = 1085.6f / sqrtf(DSD2 + us * us);
            s4[u & 1][u >> 1][vv] = sino[(v0 + vv) * NU + u] * cw;
        }
    }
    __syncthreads();

    if (t < 184) {
        const int pj = (t < 92) ? 1 : 0;
        const int J0 = (t < 92) ? t : t - 92;
        const int q = 1 - pj;
        float acc[4][4];
        #pragma unroll
        for (int r = 0; r < 4; ++r)
            #pragma unroll
            for (int vv = 0; vv < 4; ++vv) acc[r][vv] = 0.0f;

        const int ibase0 = J0 + 367 + pj;
        #pragma unroll 4
        for (int m = 0; m < 368; ++m) {
            const float4 sv = *(const float4*)&s4[q][m][0];
            const int ib = ibase0 - m;
            const float w0 = wco[ib];
            const float w1 = wco[ib + 92];
            const float w2 = wco[ib + 184];
            const float w3 = wco[ib + 276];
            acc[0][0] = fmaf(w0, sv.x, acc[0][0]);
            acc[0][1] = fmaf(w0, sv.y, acc[0][1]);
            acc[0][2] = fmaf(w0, sv.z, acc[0][2]);
            acc[0][3] = fmaf(w0, sv.w, acc[0][3]);
            acc[1][0] = fmaf(w1, sv.x, acc[1][0]);
            acc[1][1] = fmaf(w1, sv.y, acc[1][1]);
            acc[1][2] = fmaf(w1, sv.z, acc[1][2]);
            acc[1][3] = fmaf(w1, sv.w, acc[1][3]);
            acc[2][0] = fmaf(w2, sv.x, acc[2][0]);
            acc[2][1] = fmaf(w2, sv.y, acc[2][1]);
            acc[2][2] = fmaf(w2, sv.z, acc[2][2]);
            acc[2][3] = fmaf(w2, sv.w, acc[2][3]);
            acc[3][0] = fmaf(w3, sv.x, acc[3][0]);
            acc[3][1] = fmaf(w3, sv.y, acc[3][1]);
            acc[3][2] = fmaf(w3, sv.z, acc[3][2]);
            acc[3][3] = fmaf(w3, sv.w, acc[3][3]);
        }
        const float H0 = (float)(1.0 / (4.0 * 1.2858 * 1.2858));
        #pragma unroll
        for (int r = 0; r < 4; ++r) {
            const float4 c = *(const float4*)&s4[pj][J0 + 92 * r][0];
            acc[r][0] = fmaf(H0, c.x, acc[r][0]);
            acc[r][1] = fmaf(H0, c.y, acc[r][1]);
            acc[r][2] = fmaf(H0, c.z, acc[r][2]);
            acc[r][3] = fmaf(H0, c.w, acc[r][3]);
        }
        #pragma unroll
        for (int r = 0; r < 4; ++r) {
            const int j = 2 * (J0 + 92 * r) + pj;
            #pragma unroll
            for (int vv = 0; vv < 4; ++vv)
                Q[(v0 + vv) * NU + j] = acc[r][vv] * 1.2858f;
        }
    }
}

// ---------------- Stage 3: backprojection — 4-fold symmetry, 8-way view split ----------
// R10 lesson: 1024 blocks = 16 waves/CU ceiling + exterior stragglers (720 divergent
// loads/wave) left VALUBusy at 43%. This round: 8 view-chunks (stride-8 partition) ->
// 2048 blocks = 32 waves/CU target; exterior waves halve to 360 divergent loads.
// Per-view arithmetic is UNCHANGED from R10 (which passed at absmax 3.05e-4); only the
// atomic summation order differs (R3->R5 showed that's absmax-neutral).
// Symmetry identity and window proof: see R10 comment (unchanged).
// EXTERIOR: R7-bit-exact chains (R4 lesson). 1 px/lane everywhere (R5 lesson).
__global__ __launch_bounds__(256) void bp_kernel(const float* __restrict__ Q,
                                                 const float4* __restrict__ trig,
                                                 float* __restrict__ out) {
    const int b = blockIdx.x;
    const int c = b & 7;                      // view chunk (stride-8 partition)
    const int blk = b >> 3;                   // 256 quadrant blocks of 16x16
    const int bx = blk >> 4;
    const int by = blk & 15;
    const int t = threadIdx.x;
    const int w = t >> 6;
    const int l = t & 63;
    const int iq = (bx << 4) + ((w >> 1) << 3) + (l >> 3);   // [0,256)
    const int jq = (by << 4) + ((w & 1) << 3) + (l & 7);     // [0,256)

    const float dx = 400.0f / 512.0f;         // 0.78125 exact
    const float X = ((float)iq - 255.5f) * dx;   // < 0
    const float Y = ((float)jq - 255.5f) * dx;   // < 0
    const float Kc = (float)(1085.6 / 1.2858);

    float acc0 = 0.0f, acc1 = 0.0f, acc2 = 0.0f, acc3 = 0.0f;
    const bool inr = fmaf(X, X, Y * Y) <= 236.5f * 236.5f;

    if (__all(inr)) {
        // ---- interior: base views {c, c+8, ...} in [0,180); rows v, v+180, v+360, v+540
        const int nk = (c < 4) ? 23 : 22;     // ceil((180-c)/8)
        const float* qv0 = Q + c * NU;
        const float* qv1 = qv0 + 180 * NU;
        const float* qv2 = qv0 + 360 * NU;
        const float* qv3 = qv0 + 540 * NU;
        const float4* tvp = trig + c;
        for (int it = 0; it < nk; ++it) {
            const float4 tv = *tvp;                       // cb = tv.z, sb = tv.w
            float a = fmaf(tv.z, X, tv.w * Y);            // t0
            float bb = fmaf(tv.z, Y, -tv.w * X);          // s0
            float aK = a * Kc, bK = bb * Kc;
            float D0 = 595.0f - bb, D1 = 595.0f + a, D2 = 595.0f + bb, D3 = 595.0f - a;
            float r0 = __builtin_amdgcn_rcpf(D0);
            float r1 = __builtin_amdgcn_rcpf(D1);
            float r2 = __builtin_amdgcn_rcpf(D2);
            float r3 = __builtin_amdgcn_rcpf(D3);
            float fi0 = fmaf(aK,  r0, 367.5f);
            float fi1 = fmaf(bK,  r1, 367.5f);
            float fi2 = fmaf(-aK, r2, 367.5f);
            float fi3 = fmaf(-bK, r3, 367.5f);
            int i0 = (int)fi0, i1 = (int)fi1, i2 = (int)fi2, i3 = (int)fi3;
            float f0 = __builtin_amdgcn_fractf(fi0);
            float f1 = __builtin_amdgcn_fractf(fi1);
            float f2 = __builtin_amdgcn_fractf(fi2);
            float f3 = __builtin_amdgcn_fractf(fi3);
            int b0 = min(max(__builtin_amdgcn_readfirstlane(i0) - 32, 0), NU - 64);
            int b1 = min(max(__builtin_amdgcn_readfirstlane(i1) - 32, 0), NU - 64);
            int b2 = min(max(__builtin_amdgcn_readfirstlane(i2) - 32, 0), NU - 64);
            int b3 = min(max(__builtin_amdgcn_readfirstlane(i3) - 32, 0), NU - 64);
            int base[4] = {b0, b1, b2, b3};
            int rel4[4] = {(i0 - b0) << 2, (i1 - b1) << 2, (i2 - b2) << 2, (i3 - b3) << 2};
            float ff[4] = {f0, f1, f2, f3};
            float gg[4] = {r0 * r0, r1 * r1, r2 * r2, r3 * r3};
            float qw[4][4];
            #pragma unroll
            for (int m = 0; m < 4; ++m) {
                int off = base[m] + l;                    // uniform base + lane
                qw[m][0] = qv0[off];                      // coalesced dword loads
                qw[m][1] = qv1[off];
                qw[m][2] = qv2[off];
                qw[m][3] = qv3[off];
            }
            float* accp[4] = {&acc0, &acc1, &acc2, &acc3};
            #pragma unroll
            for (int m = 0; m < 4; ++m) {
                #pragma unroll
                for (int k = 0; k < 4; ++k) {
                    float q0 = __hip_ds_bpermutef(rel4[m], qw[m][k]);
                    float q1 = __hip_ds_bpermutef(rel4[m] + 4, qw[m][k]);
                    float val = fmaf(ff[m], q1 - q0, q0);
                    *accp[(m - k) & 3] = fmaf(gg[m], val, *accp[(m - k) & 3]);
                }
            }
            qv0 += 8 * NU; qv1 += 8 * NU; qv2 += 8 * NU; qv3 += 8 * NU;
            tvp += 8;
        }
    } else {
        // ---- exterior: R7-exact chains; views {c, c+8, ..., c+712} (90 iters) --------
        const float pX[4] = {X, Y, -X, -Y};
        const float pY[4] = {Y, -X, -Y, X};
        float* accp[4] = {&acc0, &acc1, &acc2, &acc3};
        const float* qr = Q + c * NU;
        const float4* tvp = trig + c;
        for (int u = 0; u < 90; ++u) {
            const float4 tv = *tvp;
            #pragma unroll
            for (int m = 0; m < 4; ++m) {
                float Xm = pX[m], Ym = pY[m];
                float t2 = fmaf(tv.x, Xm, tv.y * Ym);               // R3-exact
                float D  = fmaf(tv.w, Xm, fmaf(tv.z, -Ym, 595.0f)); // R3-exact
                float rD = __builtin_amdgcn_rcpf(D);
                float fidx = fmaf(t2, rD, 367.5f);
                int i0 = (int)fidx;
                int i0c = min(max(i0, 0), NU - 2);                  // v_med3_i32
                float f = __builtin_amdgcn_fractf(fidx);
                float2 qq = *(const float2*)(qr + i0c);             // divergent dwordx2
                float val = fmaf(f, qq.y - qq.x, qq.x);
                float g = rD * rD;
                float cen = fidx - 367.5f;
                g = (__builtin_fabsf(cen) <= 367.5f) ? g : 0.0f;
                *accp[m] = fmaf(g, val, *accp[m]);
            }
            qr += 8 * NU;
            tvp += 8;
        }
    }
    const float SC = (float)(595.0 * 595.0 * 0.5 * (2.0 * M_PI / 720.0));
    const int ir = 511 - iq, jr = 511 - jq;
    unsafeAtomicAdd(&out[iq * NXY + jq], acc0 * SC);   // P0 = (iq, jq)
    unsafeAtomicAdd(&out[jq * NXY + ir], acc1 * SC);   // P1 = (jq, 511-iq)
    unsafeAtomicAdd(&out[ir * NXY + jr], acc2 * SC);   // P2 = (511-iq, 511-jq)
    unsafeAtomicAdd(&out[jr * NXY + iq], acc3 * SC);   // P3 = (511-jq, iq)
}

extern "C" void kernel_launch(void* const* d_in, const int* in_sizes, int n_in,
                              void* d_out, int out_size, void* d_ws, size_t ws_size,
                              hipStream_t stream) {
    const float* sino = (const float*)d_in[0];
    float* out = (float*)d_out;
    float* Q = (float*)d_ws;                                          // 720*736*4 = 2.12 MB
    float4* trig = (float4*)((char*)d_ws + NV * NU * sizeof(float));  // +11.5 KB (16B aligned)

    filter_kernel<<<NV / 4, 192, 0, stream>>>(sino, Q, trig);
    hipMemsetAsync(out, 0, (size_t)NXY * NXY * sizeof(float), stream);  // atomic targets
    bp_kernel<<<2048, 256, 0, stream>>>(Q, trig, out);
}